// Round 6
// baseline (294.380 us; speedup 1.0000x reference)
//
#include <hip/hip_runtime.h>
#include <hip/hip_fp16.h>

#define BB 16
#define NN 512
#define DD 64
#define ROWS (BB * NN)   // 8192
#define NBLK 512
#define NTHR 256
#define RB 16            // rows per block (phase A)
#define JCH 32           // j-chunks per sample (phase B)
#define CHUNK (NN / JCH) // 16 sources per chunk

static __device__ __forceinline__ __half2 h2bits(unsigned int u) {
    union { unsigned int i; __half2 h; } c; c.i = u; return c.h;
}
static __device__ __forceinline__ unsigned int bits2(__half2 h) {
    union { __half2 h; unsigned int i; } c; c.h = h; return c.i;
}
// acc += sign2 * |u2 + v2|   (v_pk_add_f16, v_and_b32, v_pk_fma_f16)
static __device__ __forceinline__ __half2 absterm(unsigned int s, unsigned int u,
                                                  unsigned int v, __half2 a) {
    return __hfma2(h2bits(s), __habs2(__hadd2(h2bits(u), h2bits(v))), a);
}

// grid-wide barrier: all NBLK blocks are co-resident (LDS 40KB -> >=4 blocks/CU).
static __device__ __forceinline__ void grid_barrier(unsigned int* cnt, unsigned int* flag) {
    __threadfence();              // drain + make this block's stores agent-visible
    __syncthreads();
    if (threadIdx.x == 0) {
        const unsigned int old =
            __hip_atomic_fetch_add(cnt, 1u, __ATOMIC_ACQ_REL, __HIP_MEMORY_SCOPE_AGENT);
        if (old == NBLK - 1) {
            __hip_atomic_store(flag, 1u, __ATOMIC_RELEASE, __HIP_MEMORY_SCOPE_AGENT);
        } else {
            while (__hip_atomic_load(flag, __ATOMIC_ACQUIRE, __HIP_MEMORY_SCOPE_AGENT) == 0u)
                __builtin_amdgcn_s_sleep(2);
        }
    }
    __syncthreads();
    __threadfence();              // acquire side for all threads of the block
}

// One fused kernel: A) transforms, B) streaming scores+softmax partials, C) combine.
__global__ __launch_bounds__(NTHR, 2) void fused_gat(
    const float* __restrict__ x,
    const float* __restrict__ Wl, const float* __restrict__ bl,
    const float* __restrict__ Wr, const float* __restrict__ br,
    const float* __restrict__ att, const float* __restrict__ bias,
    const float* __restrict__ Wf, const float* __restrict__ bf,
    unsigned int* __restrict__ uh, unsigned int* __restrict__ vh,
    float2* __restrict__ epj, float2* __restrict__ part,
    unsigned int* __restrict__ sgnh, float* __restrict__ cterm,
    unsigned int* __restrict__ sync_area,
    float* __restrict__ out)
{
    __shared__ float wt[64][132];      // W^T: wt[k][c], c<64 = Wl col, c>=64 = Wr col
    __shared__ float xst[64][20];      // x^T tile: xst[k][row], 16 rows
    __shared__ float red[16][16][2];   // phase A dots / phase C partial sums

    const int tid = threadIdx.x;
    const int blk = blockIdx.x;
    const int b   = blk >> 5;          // sample 0..15 (32 blocks per sample)

    // ================= Phase A: node transforms (16 rows/block) =================
    const int r0 = blk * RB;

    #pragma unroll
    for (int t = 0; t < 8; ++t) {
        const int idx = t * 256 + tid;
        const int c   = idx & 127;
        const int k4  = (idx >> 7) << 2;
        const float* src = (c < 64) ? (Wl + c * DD + k4) : (Wr + (c - 64) * DD + k4);
        const float4 v = *reinterpret_cast<const float4*>(src);
        wt[k4 + 0][c] = v.x;
        wt[k4 + 1][c] = v.y;
        wt[k4 + 2][c] = v.z;
        wt[k4 + 3][c] = v.w;
    }
    {
        const int row = tid >> 4;          // 0..15
        const int k4  = (tid & 15) << 2;
        const float4 v = *reinterpret_cast<const float4*>(&x[(size_t)(r0 + row) * DD + k4]);
        xst[k4 + 0][row] = v.x;
        xst[k4 + 1][row] = v.y;
        xst[k4 + 2][row] = v.z;
        xst[k4 + 3][row] = v.w;
    }
    __syncthreads();

    {
        const int g  = tid & 31;        // col group (4 cols), c0 in [0,128)
        const int rp = tid >> 5;        // row pair 0..7
        const int c0 = g * 4;
        const int ra = rp * 2;
        const bool isL = (c0 < 64);
        const int d0 = c0 & 63;

        const float4 bv = *reinterpret_cast<const float4*>((isL ? bl : br) + d0);
        float acc[2][4];
        #pragma unroll
        for (int r = 0; r < 2; ++r) {
            acc[r][0] = bv.x; acc[r][1] = bv.y; acc[r][2] = bv.z; acc[r][3] = bv.w;
        }

        #pragma unroll 4
        for (int k = 0; k < 64; ++k) {
            const float4 w4 = *reinterpret_cast<const float4*>(&wt[k][c0]);
            const float2 x2 = *reinterpret_cast<const float2*>(&xst[k][ra]);
            acc[0][0] = fmaf(x2.x, w4.x, acc[0][0]);
            acc[0][1] = fmaf(x2.x, w4.y, acc[0][1]);
            acc[0][2] = fmaf(x2.x, w4.z, acc[0][2]);
            acc[0][3] = fmaf(x2.x, w4.w, acc[0][3]);
            acc[1][0] = fmaf(x2.y, w4.x, acc[1][0]);
            acc[1][1] = fmaf(x2.y, w4.y, acc[1][1]);
            acc[1][2] = fmaf(x2.y, w4.z, acc[1][2]);
            acc[1][3] = fmaf(x2.y, w4.w, acc[1][3]);
        }

        const float4 av = *reinterpret_cast<const float4*>(&att[d0]);

        if (isL) {
            const float4 wfv = *reinterpret_cast<const float4*>(&Wf[d0]);
            #pragma unroll
            for (int r = 0; r < 2; ++r) {
                red[ra + r][g][0] = av.x * acc[r][0] + av.y * acc[r][1] + av.z * acc[r][2] + av.w * acc[r][3];
                red[ra + r][g][1] = wfv.x * acc[r][0] + wfv.y * acc[r][1] + wfv.z * acc[r][2] + wfv.w * acc[r][3];
            }
        }

        // chunk-major packed writes: dst[((b*8+q)*512 + i)*4 + slot]
        unsigned int* const dst = isL ? vh : uh;
        const int q    = d0 >> 3;
        const int slot = (d0 & 4) ? 2 : 0;
        const int base = (b * 8 + q) * 512 + (r0 & 511);
        #pragma unroll
        for (int r = 0; r < 2; ++r) {
            uint2 pk;
            pk.x = bits2(__floats2half2_rn(0.4f * av.x * acc[r][0], 0.4f * av.y * acc[r][1]));
            pk.y = bits2(__floats2half2_rn(0.4f * av.z * acc[r][2], 0.4f * av.w * acc[r][3]));
            *reinterpret_cast<uint2*>(&dst[(size_t)(base + ra + r) * 4 + slot]) = pk;
        }
    }
    __syncthreads();

    if (tid < RB) {
        float a = 0.f, p = 0.f;
        #pragma unroll
        for (int gg = 0; gg < 16; ++gg) {
            a += red[tid][gg][0];
            p += red[tid][gg][1];
        }
        const float E = __expf(0.6f * a);
        epj[r0 + tid] = make_float2(E, E * p);
    }

    if (blk == 0) {
        if (tid < 32) {
            const float s0 = (att[2 * tid]     >= 0.f) ? 1.f : -1.f;
            const float s1 = (att[2 * tid + 1] >= 0.f) ? 1.f : -1.f;
            sgnh[tid] = bits2(__floats2half2_rn(s0, s1));
        }
        if (tid == 0) {
            float ct = bf[0];
            #pragma unroll 8
            for (int d = 0; d < DD; ++d) ct = fmaf(bias[d], Wf[d], ct);
            *cterm = ct;
        }
    }

    grid_barrier(&sync_area[0], &sync_area[1]);

    // ===== Phase B: streaming scores; thread owns 2 targets (i, i+256) =====
    {
        const int jc = blk & 31;
        const int i0 = tid;
        const int i1 = tid + 256;

        uint4 uu0[8], uu1[8];
        #pragma unroll
        for (int q = 0; q < 8; ++q) {
            uu0[q] = *reinterpret_cast<const uint4*>(&uh[(size_t)(((b * 8 + q) << 9) + i0) * 4]);
            uu1[q] = *reinterpret_cast<const uint4*>(&uh[(size_t)(((b * 8 + q) << 9) + i1) * 4]);
        }
        uint4 sg[8];
        #pragma unroll
        for (int q = 0; q < 8; ++q)
            sg[q] = reinterpret_cast<const uint4*>(sgnh)[q];

        float s0 = 0.f, sp0 = 0.f, s1 = 0.f, sp1 = 0.f;
        const int j0 = jc * CHUNK;

        #pragma unroll 2
        for (int jj = 0; jj < CHUNK; ++jj) {
            const int j = j0 + jj;
            __half2 a0 = __float2half2_rn(0.f), a1 = a0, b0 = a0, b1 = a0;
            #pragma unroll
            for (int q = 0; q < 8; ++q) {
                const uint4 vq = *reinterpret_cast<const uint4*>(
                    &vh[(size_t)(((b * 8 + q) << 9) + j) * 4]);   // wave-uniform
                a0 = absterm(sg[q].x, uu0[q].x, vq.x, a0);
                a1 = absterm(sg[q].y, uu0[q].y, vq.y, a1);
                a0 = absterm(sg[q].z, uu0[q].z, vq.z, a0);
                a1 = absterm(sg[q].w, uu0[q].w, vq.w, a1);
                b0 = absterm(sg[q].x, uu1[q].x, vq.x, b0);
                b1 = absterm(sg[q].y, uu1[q].y, vq.y, b1);
                b0 = absterm(sg[q].z, uu1[q].z, vq.z, b0);
                b1 = absterm(sg[q].w, uu1[q].w, vq.w, b1);
            }
            const __half2 ha = __hadd2(a0, a1);
            const __half2 hb = __hadd2(b0, b1);
            const float fa = __low2float(ha) + __high2float(ha);
            const float fb = __low2float(hb) + __high2float(hb);
            const float ta = __expf(fa);
            const float tb = __expf(fb);
            const float2 ep = epj[(b << 9) + j];                   // wave-uniform
            s0  = fmaf(ta, ep.x, s0);
            sp0 = fmaf(ta, ep.y, sp0);
            s1  = fmaf(tb, ep.x, s1);
            sp1 = fmaf(tb, ep.y, sp1);
        }
        const size_t pbase = (size_t)(((b << 5) + jc) << 9);
        part[pbase + i0] = make_float2(s0, sp0);
        part[pbase + i1] = make_float2(s1, sp1);
    }

    grid_barrier(&sync_area[2], &sync_area[3]);

    // ===== Phase C: combine partials; block handles 16 output rows =====
    {
        const float ct = *cterm;
        const int row = tid & 15;
        const int jcp = tid >> 4;              // 0..15, covers jcp and jcp+16
        const int i   = (blk & 31) * 16 + row;

        const float2 v1 = part[(size_t)(((b << 5) + jcp) << 9) + i];
        const float2 v2 = part[(size_t)(((b << 5) + jcp + 16) << 9) + i];
        red[row][jcp][0] = v1.x + v2.x;
        red[row][jcp][1] = v1.y + v2.y;
        __syncthreads();

        if (tid < 16) {
            float s = 0.f, sp = 0.f;
            #pragma unroll
            for (int c = 0; c < 16; ++c) {
                s  += red[tid][c][0];
                sp += red[tid][c][1];
            }
            out[blk * 16 + tid] = sp / s + ct;
        }
    }
}

extern "C" void kernel_launch(void* const* d_in, const int* in_sizes, int n_in,
                              void* d_out, int out_size, void* d_ws, size_t ws_size,
                              hipStream_t stream) {
    const float* x    = (const float*)d_in[0];
    const float* Wl   = (const float*)d_in[1];
    const float* bl   = (const float*)d_in[2];
    const float* Wr   = (const float*)d_in[3];
    const float* br   = (const float*)d_in[4];
    const float* att  = (const float*)d_in[5];
    const float* bias = (const float*)d_in[6];
    const float* Wf   = (const float*)d_in[7];
    const float* bf   = (const float*)d_in[8];
    float* out = (float*)d_out;

    unsigned char* ws = (unsigned char*)d_ws;
    unsigned int* uh   = (unsigned int*)ws;                     // ROWS*32 u32 (1 MB)
    unsigned int* vh   = uh + (size_t)ROWS * 32;                // ROWS*32 u32 (1 MB)
    float2*       part = (float2*)(vh + (size_t)ROWS * 32);     // B*JCH*NN float2 (2 MB)
    float2*       epj  = part + (size_t)BB * JCH * NN;          // ROWS float2 (64 KB)
    unsigned int* sgnh = (unsigned int*)(epj + ROWS);           // 32 u32
    float*        ctp  = (float*)(sgnh + 32);                   // 1 float
    unsigned int* sync_area = (unsigned int*)(ctp + 16);        // 4 u32 (padded)

    hipMemsetAsync(sync_area, 0, 64, stream);
    fused_gat<<<NBLK, NTHR, 0, stream>>>(x, Wl, bl, Wr, br, att, bias, Wf, bf,
                                         uh, vh, epj, part, sgnh, ctp, sync_area, out);
}

// Round 7
// 34.630 us; speedup vs baseline: 8.5006x; 8.5006x over previous
//
#include <hip/hip_runtime.h>
#include <hip/hip_fp16.h>

#define BB 16
#define NN 512
#define DD 64
#define ROWS (BB * NN)   // 8192
#define RB 16            // rows per k1 block
#define JCH 32           // j-chunks per sample in k2
#define CHUNK (NN / JCH) // 16 sources per chunk

static __device__ __forceinline__ __half2 h2bits(unsigned int u) {
    union { unsigned int i; __half2 h; } c; c.i = u; return c.h;
}
static __device__ __forceinline__ unsigned int bits2(__half2 h) {
    union { __half2 h; unsigned int i; } c; c.h = h; return c.i;
}
// acc += sign2 * |u2 + v2|   (v_pk_add_f16, v_and_b32, v_pk_fma_f16)
static __device__ __forceinline__ __half2 absterm(unsigned int s, unsigned int u,
                                                  unsigned int v, __half2 a) {
    return __hfma2(h2bits(s), __habs2(__hadd2(h2bits(u), h2bits(v))), a);
}

// ---------------- Kernel 0: prep (W transpose + constants) ----------------
// wtg[k][c] (c<64: Wl col c; c>=64: Wr col c-64), sgnh, cterm. 8 blocks x 256.
__global__ __launch_bounds__(256) void k0_prep(
    const float* __restrict__ Wl, const float* __restrict__ Wr,
    const float* __restrict__ att, const float* __restrict__ bias,
    const float* __restrict__ Wf, const float* __restrict__ bf,
    float* __restrict__ wtg, unsigned int* __restrict__ sgnh,
    float* __restrict__ cterm)
{
    const int idx = blockIdx.x * 256 + threadIdx.x;   // 0..2047 float4 chunks
    const int c   = idx >> 4;                         // 0..127
    const int k4  = (idx & 15) << 2;
    const float* src = (c < 64) ? (Wl + c * DD + k4) : (Wr + (c - 64) * DD + k4);
    const float4 v = *reinterpret_cast<const float4*>(src);
    wtg[(k4 + 0) * 128 + c] = v.x;
    wtg[(k4 + 1) * 128 + c] = v.y;
    wtg[(k4 + 2) * 128 + c] = v.z;
    wtg[(k4 + 3) * 128 + c] = v.w;

    if (blockIdx.x == 0) {
        const int tid = threadIdx.x;
        if (tid < 32) {
            const float s0 = (att[2 * tid]     >= 0.f) ? 1.f : -1.f;
            const float s1 = (att[2 * tid + 1] >= 0.f) ? 1.f : -1.f;
            sgnh[tid] = bits2(__floats2half2_rn(s0, s1));
        }
        if (tid == 0) {
            float ct = bf[0];
            #pragma unroll 8
            for (int d = 0; d < DD; ++d) ct = fmaf(bias[d], Wf[d], ct);
            *cterm = ct;
        }
    }
}

// ---------------- Kernel 1: node transforms ----------------
// 512 blocks x 256 thr; block = 16 rows; thread = 2 rows x 4 cols.
// W^T read straight from global (L2-resident, coalesced); x broadcast from LDS.
__global__ __launch_bounds__(256) void k1_transform(
    const float* __restrict__ x, const float* __restrict__ wtg,
    const float* __restrict__ bl, const float* __restrict__ br,
    const float* __restrict__ att, const float* __restrict__ Wf,
    unsigned int* __restrict__ uh, unsigned int* __restrict__ vh,
    float2* __restrict__ epj)
{
    __shared__ float xst[64][20];      // x^T tile: xst[k][row], 16 rows
    __shared__ float red[16][16][2];   // axl/pxl partials

    const int tid = threadIdx.x;
    const int r0 = blockIdx.x * RB;
    const int b  = blockIdx.x >> 5;    // sample

    // stage x tile transposed (coalesced global read)
    {
        const int row = tid >> 4;            // 0..15
        const int k4  = (tid & 15) << 2;
        const float4 v = *reinterpret_cast<const float4*>(&x[(size_t)(r0 + row) * DD + k4]);
        xst[k4 + 0][row] = v.x;
        xst[k4 + 1][row] = v.y;
        xst[k4 + 2][row] = v.z;
        xst[k4 + 3][row] = v.w;
    }
    __syncthreads();

    const int g  = tid & 31;        // col group (4 cols), c0 in [0,128)
    const int rq = tid >> 5;        // 0..7 -> rows ra, ra+1
    const int c0 = g * 4;
    const int ra = rq * 2;
    const bool isL = (c0 < 64);
    const int d0 = c0 & 63;

    const float4 bv = *reinterpret_cast<const float4*>((isL ? bl : br) + d0);
    float acc[2][4];
    #pragma unroll
    for (int r = 0; r < 2; ++r) {
        acc[r][0] = bv.x; acc[r][1] = bv.y; acc[r][2] = bv.z; acc[r][3] = bv.w;
    }

    #pragma unroll 4
    for (int k = 0; k < 64; ++k) {
        const float4 w4 = *reinterpret_cast<const float4*>(&wtg[k * 128 + c0]);  // global
        const float2 x2 = *reinterpret_cast<const float2*>(&xst[k][ra]);          // LDS bcast
        acc[0][0] = fmaf(x2.x, w4.x, acc[0][0]);
        acc[0][1] = fmaf(x2.x, w4.y, acc[0][1]);
        acc[0][2] = fmaf(x2.x, w4.z, acc[0][2]);
        acc[0][3] = fmaf(x2.x, w4.w, acc[0][3]);
        acc[1][0] = fmaf(x2.y, w4.x, acc[1][0]);
        acc[1][1] = fmaf(x2.y, w4.y, acc[1][1]);
        acc[1][2] = fmaf(x2.y, w4.z, acc[1][2]);
        acc[1][3] = fmaf(x2.y, w4.w, acc[1][3]);
    }

    const float4 av = *reinterpret_cast<const float4*>(&att[d0]);

    if (isL) {
        const float4 wfv = *reinterpret_cast<const float4*>(&Wf[d0]);
        #pragma unroll
        for (int r = 0; r < 2; ++r) {
            red[ra + r][g][0] = av.x * acc[r][0] + av.y * acc[r][1] + av.z * acc[r][2] + av.w * acc[r][3];
            red[ra + r][g][1] = wfv.x * acc[r][0] + wfv.y * acc[r][1] + wfv.z * acc[r][2] + wfv.w * acc[r][3];
        }
    }

    // chunk-major packed writes: dst[((b*8+q)*512 + i)*4 + slot]
    unsigned int* const dst = isL ? vh : uh;
    const int q    = d0 >> 3;
    const int slot = (d0 & 4) ? 2 : 0;
    const int base = (b * 8 + q) * 512 + (r0 & 511);
    #pragma unroll
    for (int r = 0; r < 2; ++r) {
        uint2 pk;
        pk.x = bits2(__floats2half2_rn(0.4f * av.x * acc[r][0], 0.4f * av.y * acc[r][1]));
        pk.y = bits2(__floats2half2_rn(0.4f * av.z * acc[r][2], 0.4f * av.w * acc[r][3]));
        *reinterpret_cast<uint2*>(&dst[(size_t)(base + ra + r) * 4 + slot]) = pk;
    }
    __syncthreads();

    if (tid < RB) {
        float a = 0.f, p = 0.f;
        #pragma unroll
        for (int gg = 0; gg < 16; ++gg) {
            a += red[tid][gg][0];
            p += red[tid][gg][1];
        }
        const float E = __expf(0.6f * a);
        epj[r0 + tid] = make_float2(E, E * p);
    }
}

// ---------------- Kernel 2: online-softmax streaming scores ----------------
// grid: B * JCH = 512 blocks, 512 threads; thread owns TARGET i (u-row in regs).
// Streams CHUNK sources j: t = exp(sum_d sgn|u+v|); s += t*Ej; sp += t*Pj.
__global__ __launch_bounds__(512, 2) void k2_attn(
    const unsigned int* __restrict__ uh, const unsigned int* __restrict__ vh,
    const float2* __restrict__ epj, const unsigned int* __restrict__ sgnh,
    float2* __restrict__ part)
{
    const int b  = blockIdx.x >> 5;
    const int jc = blockIdx.x & 31;
    const int i  = threadIdx.x;

    uint4 uu[8];
    #pragma unroll
    for (int q = 0; q < 8; ++q)
        uu[q] = *reinterpret_cast<const uint4*>(&uh[(size_t)(((b * 8 + q) << 9) + i) * 4]);

    uint4 sg[8];
    #pragma unroll
    for (int q = 0; q < 8; ++q)
        sg[q] = reinterpret_cast<const uint4*>(sgnh)[q];

    float s = 0.f, sp = 0.f;
    const int j0 = jc * CHUNK;

    #pragma unroll 4
    for (int jj = 0; jj < CHUNK; ++jj) {
        const int j = j0 + jj;
        __half2 a0 = __float2half2_rn(0.f), a1 = a0;
        #pragma unroll
        for (int q = 0; q < 8; ++q) {
            const uint4 vq = *reinterpret_cast<const uint4*>(
                &vh[(size_t)(((b * 8 + q) << 9) + j) * 4]);   // wave-uniform
            a0 = absterm(sg[q].x, uu[q].x, vq.x, a0);
            a1 = absterm(sg[q].y, uu[q].y, vq.y, a1);
            a0 = absterm(sg[q].z, uu[q].z, vq.z, a0);
            a1 = absterm(sg[q].w, uu[q].w, vq.w, a1);
        }
        const __half2 h = __hadd2(a0, a1);
        const float f = __low2float(h) + __high2float(h);
        const float t = __expf(f);
        const float2 ep = epj[(b << 9) + j];                   // wave-uniform
        s  = fmaf(t, ep.x, s);
        sp = fmaf(t, ep.y, sp);
    }
    part[(size_t)(((b << 5) + jc) << 9) + i] = make_float2(s, sp);
}

// ---------------- Kernel 3: combine partials ----------------
__global__ __launch_bounds__(256) void k3_final(
    const float2* __restrict__ part, const float* __restrict__ cterm,
    float* __restrict__ out)
{
    const int t = blockIdx.x * 256 + threadIdx.x;   // 0..8191
    const int b = t >> 9, i = t & 511;
    float s = 0.f, sp = 0.f;
    #pragma unroll
    for (int jc = 0; jc < JCH; ++jc) {
        const float2 v = part[(size_t)(((b << 5) + jc) << 9) + i];
        s  += v.x;
        sp += v.y;
    }
    out[t] = sp / s + *cterm;
}

extern "C" void kernel_launch(void* const* d_in, const int* in_sizes, int n_in,
                              void* d_out, int out_size, void* d_ws, size_t ws_size,
                              hipStream_t stream) {
    const float* x    = (const float*)d_in[0];
    const float* Wl   = (const float*)d_in[1];
    const float* bl   = (const float*)d_in[2];
    const float* Wr   = (const float*)d_in[3];
    const float* br   = (const float*)d_in[4];
    const float* att  = (const float*)d_in[5];
    const float* bias = (const float*)d_in[6];
    const float* Wf   = (const float*)d_in[7];
    const float* bf   = (const float*)d_in[8];
    float* out = (float*)d_out;

    unsigned char* ws = (unsigned char*)d_ws;
    unsigned int* uh   = (unsigned int*)ws;                     // ROWS*32 u32 (1 MB)
    unsigned int* vh   = uh + (size_t)ROWS * 32;                // ROWS*32 u32 (1 MB)
    float2*       part = (float2*)(vh + (size_t)ROWS * 32);     // B*JCH*NN float2 (2 MB)
    float2*       epj  = part + (size_t)BB * JCH * NN;          // ROWS float2 (64 KB)
    float*        wtg  = (float*)(epj + ROWS);                  // 64*128 f32 (32 KB)
    unsigned int* sgnh = (unsigned int*)(wtg + 64 * 128);       // 32 u32
    float*        ctp  = (float*)(sgnh + 32);                   // 1 float

    k0_prep<<<8, 256, 0, stream>>>(Wl, Wr, att, bias, Wf, bf, wtg, sgnh, ctp);
    k1_transform<<<ROWS / RB, 256, 0, stream>>>(x, wtg, bl, br, att, Wf, uh, vh, epj);
    k2_attn<<<BB * JCH, 512, 0, stream>>>(uh, vh, epj, sgnh, part);
    k3_final<<<ROWS / 256, 256, 0, stream>>>(part, ctp, out);
}

// Round 8
// 28.982 us; speedup vs baseline: 10.1572x; 1.1949x over previous
//
#include <hip/hip_runtime.h>
#include <hip/hip_fp16.h>

#define BB 16
#define NN 512
#define DD 64
#define ROWS (BB * NN)   // 8192
#define RB 32            // rows per k1 block
#define JCH 32           // j-chunks per sample in k2
#define CHUNK (NN / JCH) // 16 sources per chunk

typedef _Float16 v8h __attribute__((ext_vector_type(8)));
typedef float    v4f __attribute__((ext_vector_type(4)));

static __device__ __forceinline__ __half2 h2bits(unsigned int u) {
    union { unsigned int i; __half2 h; } c; c.i = u; return c.h;
}
static __device__ __forceinline__ unsigned int bits2(__half2 h) {
    union { __half2 h; unsigned int i; } c; c.h = h; return c.i;
}
// acc += sign2 * |u2 + v2|   (v_pk_add_f16, v_and_b32, v_pk_fma_f16)
static __device__ __forceinline__ __half2 absterm(unsigned int s, unsigned int u,
                                                  unsigned int v, __half2 a) {
    return __hfma2(h2bits(s), __habs2(__hadd2(h2bits(u), h2bits(v))), a);
}
// load 8 consecutive floats, convert to packed v8h
static __device__ __forceinline__ v8h load_cvt8(const float* __restrict__ p) {
    const float4 a = *reinterpret_cast<const float4*>(p);
    const float4 b = *reinterpret_cast<const float4*>(p + 4);
    v8h r;
    r[0] = (_Float16)a.x; r[1] = (_Float16)a.y; r[2] = (_Float16)a.z; r[3] = (_Float16)a.w;
    r[4] = (_Float16)b.x; r[5] = (_Float16)b.y; r[6] = (_Float16)b.z; r[7] = (_Float16)b.w;
    return r;
}

// ---------------- Kernel 1: node transforms via MFMA ----------------
// 256 blocks x 256 thr (4 waves). Block = 32 rows x 128 cols (cols 0..63 = xl
// via Wl, 64..127 = xr via Wr). Wave = 16 rows x 64 cols = 4 col-tiles x 2 K.
// A-frag: x[row][k] 8 contiguous; B-frag: W[col][k] 8 contiguous (W^T needed
// by MFMA == contiguous rows of W). acc -> LDS -> R5 pack/dot epilogue.
__global__ __launch_bounds__(256, 2) void k1_transform(
    const float* __restrict__ x,
    const float* __restrict__ Wl, const float* __restrict__ bl,
    const float* __restrict__ Wr, const float* __restrict__ br,
    const float* __restrict__ att, const float* __restrict__ bias,
    const float* __restrict__ Wf, const float* __restrict__ bf,
    unsigned int* __restrict__ uh, unsigned int* __restrict__ vh,
    float2* __restrict__ epj,
    unsigned int* __restrict__ sgnh, float* __restrict__ cterm)
{
    __shared__ float xacc[RB][132];    // fp32 transform results (32 x 128, pad)
    __shared__ float red[RB][16][2];   // axl/pxl partials

    const int tid = threadIdx.x;
    const int r0 = blockIdx.x * RB;

    // ---- MFMA phase ----
    {
        const int w    = tid >> 6;
        const int lane = tid & 63;
        const int rowhalf = w >> 1;          // 0/1: rows +0 / +16
        const int colhalf = w & 1;           // 0: xl (Wl), 1: xr (Wr)
        const int kb = (lane >> 4) * 8;      // k-subgroup base within 32-k window

        const int arow = r0 + rowhalf * 16 + (lane & 15);
        const v8h A0 = load_cvt8(&x[(size_t)arow * DD + 0  + kb]);
        const v8h A1 = load_cvt8(&x[(size_t)arow * DD + 32 + kb]);

        v4f acc[4];
        #pragma unroll
        for (int t = 0; t < 4; ++t) acc[t] = (v4f){0.f, 0.f, 0.f, 0.f};

        #pragma unroll
        for (int t = 0; t < 4; ++t) {
            const int c = colhalf * 64 + t * 16 + (lane & 15);   // global col 0..127
            const float* wrow = (c < 64) ? (Wl + (size_t)c * DD)
                                         : (Wr + (size_t)(c - 64) * DD);
            const v8h B0 = load_cvt8(wrow + 0  + kb);
            const v8h B1 = load_cvt8(wrow + 32 + kb);
            acc[t] = __builtin_amdgcn_mfma_f32_16x16x32_f16(A0, B0, acc[t], 0, 0, 0);
            acc[t] = __builtin_amdgcn_mfma_f32_16x16x32_f16(A1, B1, acc[t], 0, 0, 0);
        }

        // C layout: col = lane&15, row = (lane>>4)*4 + reg
        const int rbase = rowhalf * 16 + (lane >> 4) * 4;
        #pragma unroll
        for (int t = 0; t < 4; ++t) {
            const int col = colhalf * 64 + t * 16 + (lane & 15);
            #pragma unroll
            for (int r = 0; r < 4; ++r)
                xacc[rbase + r][col] = acc[t][r];
        }
    }
    __syncthreads();

    // ---- pack/dot epilogue (R5 structure; reads LDS + bias) ----
    {
        const int g  = tid & 31;        // col group (4 cols), c0 in [0,128)
        const int rq = tid >> 5;        // 0..7 -> rows ra..ra+3
        const int c0 = g * 4;
        const int ra = rq * 4;
        const bool isL = (c0 < 64);
        const int d0 = c0 & 63;

        const float4 bv = *reinterpret_cast<const float4*>((isL ? bl : br) + d0);
        const float4 av = *reinterpret_cast<const float4*>(&att[d0]);
        const float4 wfv = *reinterpret_cast<const float4*>(&Wf[d0]);

        unsigned int* const dst = isL ? vh : uh;
        const int q    = d0 >> 3;
        const int slot = (d0 & 4) ? 2 : 0;
        const int base = ((r0 >> 9) * 8 + q) * 512 + (r0 & 511);

        #pragma unroll
        for (int r = 0; r < 4; ++r) {
            float4 val = *reinterpret_cast<const float4*>(&xacc[ra + r][c0]);
            val.x += bv.x; val.y += bv.y; val.z += bv.z; val.w += bv.w;

            if (isL) {
                red[ra + r][g][0] = av.x * val.x + av.y * val.y + av.z * val.z + av.w * val.w;
                red[ra + r][g][1] = wfv.x * val.x + wfv.y * val.y + wfv.z * val.z + wfv.w * val.w;
            }
            uint2 pk;
            pk.x = bits2(__floats2half2_rn(0.4f * av.x * val.x, 0.4f * av.y * val.y));
            pk.y = bits2(__floats2half2_rn(0.4f * av.z * val.z, 0.4f * av.w * val.w));
            *reinterpret_cast<uint2*>(&dst[(size_t)(base + ra + r) * 4 + slot]) = pk;
        }
    }
    __syncthreads();

    if (tid < RB) {
        float a = 0.f, p = 0.f;
        #pragma unroll
        for (int gg = 0; gg < 16; ++gg) {
            a += red[tid][gg][0];
            p += red[tid][gg][1];
        }
        const float E = __expf(0.6f * a);
        epj[r0 + tid] = make_float2(E, E * p);
    }

    if (blockIdx.x == 0) {
        if (tid < 32) {
            const float s0 = (att[2 * tid]     >= 0.f) ? 1.f : -1.f;
            const float s1 = (att[2 * tid + 1] >= 0.f) ? 1.f : -1.f;
            sgnh[tid] = bits2(__floats2half2_rn(s0, s1));
        }
        if (tid == 0) {
            float ct = bf[0];
            #pragma unroll 8
            for (int d = 0; d < DD; ++d) ct = fmaf(bias[d], Wf[d], ct);
            *cterm = ct;
        }
    }
}

// ---------------- Kernel 2: online-softmax streaming scores ----------------
// grid: B * JCH = 512 blocks, 512 threads; thread owns TARGET i (u-row in regs).
// Streams CHUNK sources j: t = exp(sum_d sgn|u+v|); s += t*Ej; sp += t*Pj.
__global__ __launch_bounds__(512, 2) void k2_attn(
    const unsigned int* __restrict__ uh, const unsigned int* __restrict__ vh,
    const float2* __restrict__ epj, const unsigned int* __restrict__ sgnh,
    float2* __restrict__ part)
{
    const int b  = blockIdx.x >> 5;
    const int jc = blockIdx.x & 31;
    const int i  = threadIdx.x;

    uint4 uu[8];
    #pragma unroll
    for (int q = 0; q < 8; ++q)
        uu[q] = *reinterpret_cast<const uint4*>(&uh[(size_t)(((b * 8 + q) << 9) + i) * 4]);

    uint4 sg[8];
    #pragma unroll
    for (int q = 0; q < 8; ++q)
        sg[q] = reinterpret_cast<const uint4*>(sgnh)[q];

    float s = 0.f, sp = 0.f;
    const int j0 = jc * CHUNK;

    #pragma unroll 2
    for (int jj = 0; jj < CHUNK; ++jj) {
        const int j = j0 + jj;
        __half2 a0 = __float2half2_rn(0.f), a1 = a0;
        #pragma unroll
        for (int q = 0; q < 8; ++q) {
            const uint4 vq = *reinterpret_cast<const uint4*>(
                &vh[(size_t)(((b * 8 + q) << 9) + j) * 4]);   // wave-uniform
            a0 = absterm(sg[q].x, uu[q].x, vq.x, a0);
            a1 = absterm(sg[q].y, uu[q].y, vq.y, a1);
            a0 = absterm(sg[q].z, uu[q].z, vq.z, a0);
            a1 = absterm(sg[q].w, uu[q].w, vq.w, a1);
        }
        const __half2 h = __hadd2(a0, a1);
        const float f = __low2float(h) + __high2float(h);
        const float t = __expf(f);
        const float2 ep = epj[(b << 9) + j];                   // wave-uniform
        s  = fmaf(t, ep.x, s);
        sp = fmaf(t, ep.y, sp);
    }
    part[(size_t)(((b << 5) + jc) << 9) + i] = make_float2(s, sp);
}

// ---------------- Kernel 3: combine partials ----------------
__global__ __launch_bounds__(256) void k3_final(
    const float2* __restrict__ part, const float* __restrict__ cterm,
    float* __restrict__ out)
{
    const int t = blockIdx.x * 256 + threadIdx.x;   // 0..8191
    const int b = t >> 9, i = t & 511;
    float s = 0.f, sp = 0.f;
    #pragma unroll
    for (int jc = 0; jc < JCH; ++jc) {
        const float2 v = part[(size_t)(((b << 5) + jc) << 9) + i];
        s  += v.x;
        sp += v.y;
    }
    out[t] = sp / s + *cterm;
}

extern "C" void kernel_launch(void* const* d_in, const int* in_sizes, int n_in,
                              void* d_out, int out_size, void* d_ws, size_t ws_size,
                              hipStream_t stream) {
    const float* x    = (const float*)d_in[0];
    const float* Wl   = (const float*)d_in[1];
    const float* bl   = (const float*)d_in[2];
    const float* Wr   = (const float*)d_in[3];
    const float* br   = (const float*)d_in[4];
    const float* att  = (const float*)d_in[5];
    const float* bias = (const float*)d_in[6];
    const float* Wf   = (const float*)d_in[7];
    const float* bf   = (const float*)d_in[8];
    float* out = (float*)d_out;

    unsigned char* ws = (unsigned char*)d_ws;
    unsigned int* uh   = (unsigned int*)ws;                     // ROWS*32 u32 (1 MB)
    unsigned int* vh   = uh + (size_t)ROWS * 32;                // ROWS*32 u32 (1 MB)
    float2*       part = (float2*)(vh + (size_t)ROWS * 32);     // B*JCH*NN float2 (2 MB)
    float2*       epj  = part + (size_t)BB * JCH * NN;          // ROWS float2 (64 KB)
    unsigned int* sgnh = (unsigned int*)(epj + ROWS);           // 32 u32
    float*        ctp  = (float*)(sgnh + 32);                   // 1 float

    k1_transform<<<ROWS / RB, 256, 0, stream>>>(x, Wl, bl, Wr, br, att, bias, Wf, bf,
                                                uh, vh, epj, sgnh, ctp);
    k2_attn<<<BB * JCH, 512, 0, stream>>>(uh, vh, epj, sgnh, part);
    k3_final<<<ROWS / 256, 256, 0, stream>>>(part, ctp, out);
}